// Round 2
// baseline (585.029 us; speedup 1.0000x reference)
//
#include <hip/hip_runtime.h>
#include <hip/hip_bf16.h>

#define BB 64
#define SS 2048
#define DD 512
#define UU 512
#define BS (BB*SS)   // 131072

typedef __attribute__((ext_vector_type(8))) short bf16x8;
typedef __attribute__((ext_vector_type(4))) float f32x4;

static __device__ __forceinline__ unsigned short f2bf(float x) {
    union { float f; unsigned int u; } v; v.f = x;
    unsigned int r = v.u + 0x7FFFu + ((v.u >> 16) & 1u);
    return (unsigned short)(r >> 16);
}

// ---- fused prep: blocks 0..63 transpose W2 -> bf16 W2T[u][d]; blocks 64..127 qproj ----
__global__ void k_prep(const float* __restrict__ W2, unsigned short* __restrict__ W2T,
                       const float* __restrict__ query, const float* __restrict__ W1,
                       const float* __restrict__ b1, const float* __restrict__ b2,
                       float* __restrict__ qpb) {
    __shared__ float tile[64][65];
    const int t = threadIdx.x;
    if (blockIdx.x < 64) {
        const int ti = blockIdx.x >> 3;   // d-tile
        const int tj = blockIdx.x & 7;    // u-tile
        #pragma unroll
        for (int i = 0; i < 16; ++i) {
            int e = i*256 + t;
            int dr = e >> 6, uc = e & 63;
            tile[dr][uc] = W2[(size_t)(ti*64+dr)*UU + tj*64+uc];
        }
        __syncthreads();
        #pragma unroll
        for (int i = 0; i < 16; ++i) {
            int e = i*256 + t;
            int ur = e >> 6, dc = e & 63;
            W2T[(size_t)(tj*64+ur)*DD + ti*64+dc] = f2bf(tile[dc][ur]);
        }
    } else {
        const int b = blockIdx.x - 64;
        float a0 = 0.f, a1 = 0.f;
        for (int d = 0; d < DD; ++d) {
            float q = query[b*DD + d];
            a0 += q * W1[(size_t)d*UU + t];
            a1 += q * W1[(size_t)d*UU + t + 256];
        }
        qpb[b*UU + t]       = a0 + b1[t]     + b2[t];
        qpb[b*UU + t + 256] = a1 + b1[t+256] + b2[t+256];
    }
}

// ---- fused scores: v_proj GEMM (bf16 MFMA, pipelined B) + tanh + dot(V), direct store ----
__launch_bounds__(256, 2)
__global__ void k_scores(const float* __restrict__ values,
                         const unsigned short* __restrict__ W2T,
                         const float* __restrict__ qpb,
                         const float* __restrict__ Vw,
                         float* __restrict__ scores) {
    // 64 rows x 512 k of bf16 A-tile, XOR-swizzled in 16B granules: exactly 64 KB
    __shared__ unsigned short Albuf[64*512];
    const int t  = threadIdx.x;
    const int m0 = blockIdx.x * 64;        // global row base (b,s flattened)
    const int b  = m0 >> 11;               // 2048 rows per batch

    const int wave = t >> 6, lane = t & 63;
    const int ln15 = lane & 15, quad = lane >> 4;

    // preload epilogue constants (latency hidden under staging)
    float qv[2][4], vw[2][4];
    #pragma unroll
    for (int nc = 0; nc < 2; ++nc)
        #pragma unroll
        for (int nt = 0; nt < 4; ++nt) {
            int n = nc*256 + wave*64 + nt*16 + ln15;
            qv[nc][nt] = qpb[b*UU + n];
            vw[nc][nt] = Vw[n];
        }

    // stage A: fp32 -> bf16, swizzle granule g -> g ^ (row&7)
    const float* src = values + (size_t)m0 * DD;
    #pragma unroll
    for (int i = 0; i < 16; ++i) {
        int gf  = i*256 + t;               // granule 0..4095
        int row = gf >> 6;                 // 0..63
        int g   = gf & 63;                 // granule in row (8 bf16 each)
        const float4 f0 = *(const float4*)(src + (size_t)row*DD + g*8);
        const float4 f1 = *(const float4*)(src + (size_t)row*DD + g*8 + 4);
        ushort4 lo, hi;
        lo.x = f2bf(f0.x); lo.y = f2bf(f0.y); lo.z = f2bf(f0.z); lo.w = f2bf(f0.w);
        hi.x = f2bf(f1.x); hi.y = f2bf(f1.y); hi.z = f2bf(f1.z); hi.w = f2bf(f1.w);
        int gs = g ^ (row & 7);
        ushort4* dst = (ushort4*)&Albuf[row*512 + gs*8];
        dst[0] = lo; dst[1] = hi;
    }
    __syncthreads();

    // B row base pointers for this wave's n-slice (per nt); nc adds 256*DD, ks adds 32
    const unsigned short* bp[4];
    #pragma unroll
    for (int nt = 0; nt < 4; ++nt)
        bp[nt] = W2T + (size_t)(wave*64 + nt*16 + ln15) * DD + quad*8;

    // A LDS bases (in shorts)
    int abase[4];
    #pragma unroll
    for (int mt = 0; mt < 4; ++mt)
        abase[mt] = (mt*16 + ln15) * 512;
    const int xm = ln15 & 7;

    float sacc[4][4] = {};                 // [mt][r] running score partials

    // prologue: load B frags for j=0
    bf16x8 bb[2][4];
    #pragma unroll
    for (int nt = 0; nt < 4; ++nt)
        bb[0][nt] = *(const bf16x8*)(bp[nt]);

    for (int nc = 0; nc < 2; ++nc) {
        f32x4 acc[4][4];
        #pragma unroll
        for (int mt = 0; mt < 4; ++mt)
            #pragma unroll
            for (int nt = 0; nt < 4; ++nt)
                acc[mt][nt] = f32x4{0.f, 0.f, 0.f, 0.f};

        #pragma unroll
        for (int ks = 0; ks < 16; ++ks) {
            const int j   = nc*16 + ks;
            const int cur = j & 1;
            // prefetch next kstep's B frags (crosses nc boundary -> overlaps epilogue)
            if (j + 1 < 32) {
                const int jn  = j + 1;
                const int off = (jn >> 4) * (256*DD) + (jn & 15) * 32;
                #pragma unroll
                for (int nt = 0; nt < 4; ++nt)
                    bb[cur ^ 1][nt] = *(const bf16x8*)(bp[nt] + off);
            }
            bf16x8 afr[4];
            const int g4 = ks*4 + quad;
            #pragma unroll
            for (int mt = 0; mt < 4; ++mt)
                afr[mt] = *(const bf16x8*)&Albuf[abase[mt] + ((g4 ^ xm) << 3)];
            #pragma unroll
            for (int mt = 0; mt < 4; ++mt)
                #pragma unroll
                for (int nt = 0; nt < 4; ++nt)
                    acc[mt][nt] = __builtin_amdgcn_mfma_f32_16x16x32_bf16(
                        afr[mt], bb[cur][nt], acc[mt][nt], 0, 0, 0);
        }

        // epilogue: h = tanh(qv + vproj); sacc += h * vw   (next-nc B already in flight)
        #pragma unroll
        for (int nt = 0; nt < 4; ++nt) {
            const float q = qv[nc][nt];
            const float w = vw[nc][nt];
            #pragma unroll
            for (int mt = 0; mt < 4; ++mt)
                #pragma unroll
                for (int r = 0; r < 4; ++r) {
                    float x = q + acc[mt][nt][r];
                    float e = __expf(x + x);
                    float rc = __builtin_amdgcn_rcpf(e + 1.f);
                    sacc[mt][r] = fmaf(fmaf(-2.f, rc, 1.f), w, sacc[mt][r]);
                }
        }
    }

    // reduce 16 lanes of each quad (16 n-columns each), then cross-wave via LDS
    __syncthreads();                       // all waves done reading Albuf
    float* buf = (float*)Albuf;            // [4 waves][64 rows]
    #pragma unroll
    for (int mt = 0; mt < 4; ++mt)
        #pragma unroll
        for (int r = 0; r < 4; ++r) {
            float v = sacc[mt][r];
            v += __shfl_xor(v, 1);
            v += __shfl_xor(v, 2);
            v += __shfl_xor(v, 4);
            v += __shfl_xor(v, 8);
            if (ln15 == 0) buf[wave*64 + mt*16 + quad*4 + r] = v;
        }
    __syncthreads();
    if (t < 64)
        scores[m0 + t] = buf[t] + buf[64 + t] + buf[128 + t] + buf[192 + t];
}

// ---- fused softmax + context: per block recompute softmax(b), then weighted sum ----
__launch_bounds__(256)
__global__ void k_context(const float* __restrict__ values, const float* __restrict__ scores,
                          float* __restrict__ out) {
    __shared__ float w[SS];                // 8 KB
    __shared__ float red8[8];
    __shared__ float4 red[16][16];
    const int blk = blockIdx.x;
    const int b = blk >> 3, d0 = (blk & 7) * 64;
    const int t = threadIdx.x;

    // softmax over scores[b][0..SS)
    const float* sc = scores + b*SS;
    float v[8];
    float mx = -1e30f;
    #pragma unroll
    for (int i = 0; i < 8; ++i) { v[i] = sc[i*256 + t]; mx = fmaxf(mx, v[i]); }
    #pragma unroll
    for (int off = 32; off; off >>= 1) mx = fmaxf(mx, __shfl_xor(mx, off));
    if ((t & 63) == 0) red8[t >> 6] = mx;
    __syncthreads();
    mx = fmaxf(fmaxf(red8[0], red8[1]), fmaxf(red8[2], red8[3]));
    float sum = 0.f;
    #pragma unroll
    for (int i = 0; i < 8; ++i) { v[i] = __expf(v[i] - mx); sum += v[i]; }
    #pragma unroll
    for (int off = 32; off; off >>= 1) sum += __shfl_xor(sum, off);
    __syncthreads();
    if ((t & 63) == 0) red8[4 + (t >> 6)] = sum;
    __syncthreads();
    sum = red8[4] + red8[5] + red8[6] + red8[7];
    float inv = 1.f / sum;
    #pragma unroll
    for (int i = 0; i < 8; ++i) w[i*256 + t] = v[i] * inv;
    __syncthreads();

    // context[b][d0..d0+64) = sum_s w[s] * values[b][s][d0..]
    const int di = t & 15, sg = t >> 4;
    float4 acc = make_float4(0.f, 0.f, 0.f, 0.f);
    const float* vb = values + (size_t)b*SS*DD + d0 + di*4;
    #pragma unroll 8
    for (int s = sg; s < SS; s += 16) {
        float wgt = w[s];
        float4 vv = *(const float4*)(vb + (size_t)s*DD);
        acc.x += wgt*vv.x; acc.y += wgt*vv.y; acc.z += wgt*vv.z; acc.w += wgt*vv.w;
    }
    red[sg][di] = acc;
    __syncthreads();
    if (t < 16) {
        float4 s4 = make_float4(0.f, 0.f, 0.f, 0.f);
        #pragma unroll
        for (int g = 0; g < 16; ++g) {
            float4 vv = red[g][t];
            s4.x += vv.x; s4.y += vv.y; s4.z += vv.z; s4.w += vv.w;
        }
        *(float4*)(out + (size_t)b*DD + d0 + t*4) = s4;
    }
}

extern "C" void kernel_launch(void* const* d_in, const int* in_sizes, int n_in,
                              void* d_out, int out_size, void* d_ws, size_t ws_size,
                              hipStream_t stream) {
    const float* query  = (const float*)d_in[0];
    const float* values = (const float*)d_in[1];
    const float* W1     = (const float*)d_in[2];
    const float* b1     = (const float*)d_in[3];
    const float* W2     = (const float*)d_in[4];
    const float* b2     = (const float*)d_in[5];
    const float* Vw     = (const float*)d_in[6];
    // d_in[7] = bv: softmax over s is shift-invariant -> no-op

    char* ws = (char*)d_ws;
    unsigned short* W2T = (unsigned short*)ws;                         // 512 KB
    float* qpb    = (float*)(ws + 524288);                             // 128 KB
    float* scores = (float*)(ws + 524288 + 131072);                    // 512 KB
    float* out    = (float*)d_out;

    k_prep<<<128, 256, 0, stream>>>(W2, W2T, query, W1, b1, b2, qpb);
    k_scores<<<BS/64, 256, 0, stream>>>(values, W2T, qpb, Vw, scores);
    k_context<<<BB*8, 256, 0, stream>>>(values, scores, out);
}

// Round 3
// 510.082 us; speedup vs baseline: 1.1469x; 1.1469x over previous
//
#include <hip/hip_runtime.h>
#include <hip/hip_bf16.h>

#define BB 64
#define SS 2048
#define DD 512
#define UU 512
#define BS (BB*SS)   // 131072

typedef __attribute__((ext_vector_type(8))) short bf16x8;
typedef __attribute__((ext_vector_type(16))) float f32x16;

static __device__ __forceinline__ unsigned short f2bf(float x) {
    union { float f; unsigned int u; } v; v.f = x;
    unsigned int r = v.u + 0x7FFFu + ((v.u >> 16) & 1u);
    return (unsigned short)(r >> 16);
}

// ---- prep: blocks 0..63 pack W2 -> W2F (MFMA B-fragment-major, bf16);
//            blocks 64..127 qproj ----
// W2F granule index: ((ks*16 + ntile)*64 + lane), 8 bf16 each.
//   n = ntile*32 + (lane&31), k = ks*16 + (lane>>5)*8 + j
__global__ void k_prep(const float* __restrict__ W2, unsigned short* __restrict__ W2F,
                       const float* __restrict__ query, const float* __restrict__ W1,
                       const float* __restrict__ b1, const float* __restrict__ b2,
                       float* __restrict__ qpb) {
    __shared__ float tile[64][65];
    const int t = threadIdx.x;
    if (blockIdx.x < 64) {
        const int ti = blockIdx.x >> 3;   // d-tile (k)
        const int tj = blockIdx.x & 7;    // u-tile (n)
        #pragma unroll
        for (int i = 0; i < 16; ++i) {
            int e = i*256 + t;
            int dr = e >> 6, uc = e & 63;
            tile[dr][uc] = W2[(size_t)(ti*64+dr)*UU + tj*64+uc];
        }
        __syncthreads();
        const int ksl = t >> 6, ln = t & 63;
        const int lh = ln >> 5, l31 = ln & 31;
        #pragma unroll
        for (int ntl = 0; ntl < 2; ++ntl) {
            const int ks = ti*4 + ksl;
            const int ntile = tj*2 + ntl;
            bf16x8 g;
            #pragma unroll
            for (int j = 0; j < 8; ++j)
                g[j] = (short)f2bf(tile[ksl*16 + lh*8 + j][ntl*32 + l31]);
            *(bf16x8*)&W2F[(size_t)(((ks*16 + ntile)*64 + ln) * 8)] = g;
        }
    } else {
        const int b = blockIdx.x - 64;
        float a0 = 0.f, a1 = 0.f;
        for (int d = 0; d < DD; ++d) {
            float q = query[b*DD + d];
            a0 += q * W1[(size_t)d*UU + t];
            a1 += q * W1[(size_t)d*UU + t + 256];
        }
        qpb[b*UU + t]       = a0 + b1[t]     + b2[t];
        qpb[b*UU + t + 256] = a1 + b1[t+256] + b2[t+256];
    }
}

// ---- fused scores + per-block softmax stats + fp32 partial context ----
// 64 rows/block, N=512 (4 waves x 128), K=512, 32x32x16 MFMA, no K-loop barriers.
__launch_bounds__(256, 2)
__global__ void k_scores(const float* __restrict__ values,
                         const unsigned short* __restrict__ W2F,
                         const float* __restrict__ qpb,
                         const float* __restrict__ Vw,
                         float* __restrict__ pm, float* __restrict__ pl,
                         float* __restrict__ pv) {
    __shared__ unsigned short Albuf[64*512];   // 64 KB: A rows resident, full K
    const int t   = threadIdx.x;
    const int blk = blockIdx.x;
    const int m0  = blk * 64;
    const int b   = blk >> 5;                  // 32 blocks per batch
    const int wave = t >> 6, lane = t & 63;
    const int ln31 = lane & 31, half = lane >> 5;

    // --- B prologue: frag-contiguous coalesced loads, distance-2 pipeline ---
    const bf16x8* Bp = (const bf16x8*)W2F;
    bf16x8 bfr[2][4];
    #pragma unroll
    for (int nt = 0; nt < 4; ++nt)
        bfr[0][nt] = Bp[(0*16 + wave*4 + nt)*64 + lane];
    #pragma unroll
    for (int nt = 0; nt < 4; ++nt)
        bfr[1][nt] = Bp[(1*16 + wave*4 + nt)*64 + lane];

    // epilogue constants
    float qv[4], vw[4];
    #pragma unroll
    for (int nt = 0; nt < 4; ++nt) {
        int n = wave*128 + nt*32 + ln31;
        qv[nt] = qpb[b*UU + n];
        vw[nt] = Vw[n];
    }

    // --- stage A: fp32 -> bf16, XOR-swizzled 16B granules ---
    const float* src = values + (size_t)m0 * DD;
    #pragma unroll
    for (int i = 0; i < 16; ++i) {
        int gf  = i*256 + t;
        int row = gf >> 6;
        int g   = gf & 63;
        const float4 f0 = *(const float4*)(src + (size_t)row*DD + g*8);
        const float4 f1 = *(const float4*)(src + (size_t)row*DD + g*8 + 4);
        bf16x8 pk;
        pk[0] = (short)f2bf(f0.x); pk[1] = (short)f2bf(f0.y);
        pk[2] = (short)f2bf(f0.z); pk[3] = (short)f2bf(f0.w);
        pk[4] = (short)f2bf(f1.x); pk[5] = (short)f2bf(f1.y);
        pk[6] = (short)f2bf(f1.z); pk[7] = (short)f2bf(f1.w);
        *(bf16x8*)&Albuf[row*512 + ((g ^ (row & 7)) << 3)] = pk;
    }
    __syncthreads();

    // --- K-loop: 32 ksteps, 8 MFMA each, no barriers ---
    f32x16 acc[2][4];
    #pragma unroll
    for (int mt = 0; mt < 2; ++mt)
        #pragma unroll
        for (int nt = 0; nt < 4; ++nt)
            #pragma unroll
            for (int r = 0; r < 16; ++r)
                acc[mt][nt][r] = 0.f;

    const int xm = ln31 & 7;
    #pragma unroll 4
    for (int ks = 0; ks < 32; ++ks) {
        const int cur = ks & 1;
        const int g8 = (((ks*2 + half) ^ xm) << 3);
        bf16x8 a0 = *(const bf16x8*)&Albuf[ln31*512 + g8];
        bf16x8 a1 = *(const bf16x8*)&Albuf[16384 + ln31*512 + g8];
        #pragma unroll
        for (int nt = 0; nt < 4; ++nt) {
            acc[0][nt] = __builtin_amdgcn_mfma_f32_32x32x16_bf16(a0, bfr[cur][nt], acc[0][nt], 0, 0, 0);
            acc[1][nt] = __builtin_amdgcn_mfma_f32_32x32x16_bf16(a1, bfr[cur][nt], acc[1][nt], 0, 0, 0);
        }
        // prefetch ks+2 (W2F padded by 2 ksteps -> branchless)
        #pragma unroll
        for (int nt = 0; nt < 4; ++nt)
            bfr[cur][nt] = Bp[((ks+2)*16 + wave*4 + nt)*64 + lane];
    }

    // --- epilogue: tanh + V-dot; per-lane partials over this wave's 128 cols ---
    float sacc[2][16];
    #pragma unroll
    for (int mt = 0; mt < 2; ++mt)
        #pragma unroll
        for (int r = 0; r < 16; ++r)
            sacc[mt][r] = 0.f;
    #pragma unroll
    for (int nt = 0; nt < 4; ++nt) {
        const float q = qv[nt], w = vw[nt];
        #pragma unroll
        for (int mt = 0; mt < 2; ++mt)
            #pragma unroll
            for (int r = 0; r < 16; ++r) {
                float x = q + acc[mt][nt][r];
                float e = __expf(x + x);
                float rc = __builtin_amdgcn_rcpf(e + 1.f);
                sacc[mt][r] = fmaf(fmaf(-2.f, rc, 1.f), w, sacc[mt][r]);
            }
    }

    __syncthreads();                       // all waves done reading Albuf
    float* sred = (float*)Albuf;           // reuse LDS: [4 waves][64 rows] + stats
    #pragma unroll
    for (int mt = 0; mt < 2; ++mt)
        #pragma unroll
        for (int r = 0; r < 16; ++r) {
            float v = sacc[mt][r];
            v += __shfl_xor(v, 1);
            v += __shfl_xor(v, 2);
            v += __shfl_xor(v, 4);
            v += __shfl_xor(v, 8);
            v += __shfl_xor(v, 16);
            if (ln31 == 0)
                sred[wave*64 + mt*32 + (r & 3) + 8*(r >> 2) + 4*half] = v;
        }
    __syncthreads();

    // wave 0: full scores -> block max, exp, sum
    if (t < 64) {
        float s = sred[t] + sred[64 + t] + sred[128 + t] + sred[192 + t];
        float m = s;
        #pragma unroll
        for (int off = 32; off; off >>= 1) m = fmaxf(m, __shfl_xor(m, off));
        float p = __expf(s - m);
        float l = p;
        #pragma unroll
        for (int off = 32; off; off >>= 1) l += __shfl_xor(l, off);
        sred[256 + t] = p;
        if (t == 0) { pm[blk] = m; pl[blk] = l; }
    }
    __syncthreads();

    // partial context: ctx_d = sum_i p_i * values[m0+i][d]  (fp32 re-read, L2/L3-hot)
    float2 cacc = make_float2(0.f, 0.f);
    const float* vrow = values + (size_t)m0*DD + t*2;
    #pragma unroll 8
    for (int i = 0; i < 64; ++i) {
        float p = sred[256 + i];
        float2 v = *(const float2*)(vrow + (size_t)i*DD);
        cacc.x = fmaf(p, v.x, cacc.x);
        cacc.y = fmaf(p, v.y, cacc.y);
    }
    *(float2*)&pv[(size_t)blk*DD + t*2] = cacc;
}

// ---- finish: combine 32 chunks per batch with online-softmax rescale ----
__global__ void k_finish(const float* __restrict__ pv, const float* __restrict__ pm,
                         const float* __restrict__ pl, float* __restrict__ out) {
    __shared__ float sm_[32], sl_[32], sw[32];
    const int b = blockIdx.x, t = threadIdx.x;
    if (t < 32) { sm_[t] = pm[b*32 + t]; sl_[t] = pl[b*32 + t]; }
    __syncthreads();
    float M = -1e30f;
    #pragma unroll
    for (int c = 0; c < 32; ++c) M = fmaxf(M, sm_[c]);
    float L = 0.f;
    #pragma unroll
    for (int c = 0; c < 32; ++c) L += sl_[c] * __expf(sm_[c] - M);
    if (t < 32) sw[t] = __expf(sm_[t] - M) / L;
    __syncthreads();
    float2 a = make_float2(0.f, 0.f);
    #pragma unroll 4
    for (int c = 0; c < 32; ++c) {
        float w = sw[c];
        float2 v = *(const float2*)&pv[(size_t)(b*32 + c)*DD + t*2];
        a.x = fmaf(w, v.x, a.x);
        a.y = fmaf(w, v.y, a.y);
    }
    *(float2*)&out[(size_t)b*DD + t*2] = a;
}

extern "C" void kernel_launch(void* const* d_in, const int* in_sizes, int n_in,
                              void* d_out, int out_size, void* d_ws, size_t ws_size,
                              hipStream_t stream) {
    const float* query  = (const float*)d_in[0];
    const float* values = (const float*)d_in[1];
    const float* W1     = (const float*)d_in[2];
    const float* b1     = (const float*)d_in[3];
    const float* W2     = (const float*)d_in[4];
    const float* b2     = (const float*)d_in[5];
    const float* Vw     = (const float*)d_in[6];
    // d_in[7] = bv: softmax over s is shift-invariant -> no-op

    char* ws = (char*)d_ws;
    unsigned short* W2F = (unsigned short*)ws;            // 512 KB + 32 KB pad = 544 KB
    float* qpb = (float*)(ws + 557056);                   // 128 KB
    float* pm  = (float*)(ws + 557056 + 131072);          // 8 KB
    float* pl  = (float*)(ws + 557056 + 131072 + 8192);   // 8 KB
    float* pv  = (float*)(ws + 557056 + 131072 + 16384);  // 4 MB

    k_prep<<<128, 256, 0, stream>>>(W2, W2F, query, W1, b1, b2, qpb);
    k_scores<<<BS/64, 256, 0, stream>>>(values, W2F, qpb, Vw, pm, pl, pv);
    k_finish<<<BB, 256, 0, stream>>>(pv, pm, pl, (float*)d_out);
}